// Round 1
// 99.254 us; speedup vs baseline: 1.0103x; 1.0103x over previous
//
#include <hip/hip_runtime.h>
#include <math.h>

#define NN 256
#define LL 4096
#define DL 64
#define DC 128
#define KS 15
#define LOUT (LL - KS + 1)   // 4082
#define RSQRT_DC 0.08838834764831843f
#define INV_LOUT (1.0f / (float)LOUT)

// Inter-kernel scratch in module-scope device globals (NOT d_ws):
//   g_ctb   60*128 floats   contrib table
//   g_pack  256*256 uints   16 tokens per dword, 2 bits each
//   g_cnt   256*4  ints     total token-value counts per seq
// Coherence prep->encode is provided by dispatch-boundary acquire/release,
// exactly as the previous d_ws round-trip relied on.
__device__ __align__(16) float    g_ctb[60 * DC];
__device__ __align__(16) unsigned g_pack[NN * 256];
__device__ __align__(16) int      g_cnt[NN * 4];

// ---------------- K1: token pack+counts (blocks 0..255) + contrib table (blocks 256..383) ----------------
__global__ __launch_bounds__(256) void prep_kernel(const int* __restrict__ tokens,
                                                   const float* __restrict__ emb,
                                                   const float* __restrict__ conv_w) {
    const int b = blockIdx.x, tid = threadIdx.x;
    if (b < NN) {
        __shared__ int totw[4][4];
        const int n = b;
        const int4* tv = (const int4*)(tokens + (size_t)n * LL) + tid * 4;
        unsigned w = 0;
#pragma unroll
        for (int m = 0; m < 4; ++m) {
            int4 t4 = tv[m];
            w |= ((unsigned)t4.x | ((unsigned)t4.y << 2) |
                  ((unsigned)t4.z << 4) | ((unsigned)t4.w << 6)) << (8 * m);
        }
        g_pack[n * 256 + tid] = w;
        int c0, c1, c2, c3;
        unsigned y, z;
        y = w;               z = (y | (y >> 1)) & 0x55555555u; c0 = 16 - __popc(z);
        y = w ^ 0x55555555u; z = (y | (y >> 1)) & 0x55555555u; c1 = 16 - __popc(z);
        y = w ^ 0xAAAAAAAAu; z = (y | (y >> 1)) & 0x55555555u; c2 = 16 - __popc(z);
        y = w ^ 0xFFFFFFFFu; z = (y | (y >> 1)) & 0x55555555u; c3 = 16 - __popc(z);
#pragma unroll
        for (int off = 32; off > 0; off >>= 1) {
            c0 += __shfl_down(c0, off, 64); c1 += __shfl_down(c1, off, 64);
            c2 += __shfl_down(c2, off, 64); c3 += __shfl_down(c3, off, 64);
        }
        if ((tid & 63) == 0) {
            const int wv = tid >> 6;
            totw[wv][0] = c0; totw[wv][1] = c1; totw[wv][2] = c2; totw[wv][3] = c3;
        }
        __syncthreads();
        if (tid < 4)
            g_cnt[n * 4 + tid] =
                totw[0][tid] + totw[1][tid] + totw[2][tid] + totw[3][tid];
    } else {
        const int c = b - NN;
        __shared__ float wsm[DL][16];
        __shared__ float es[4][DL];
        const float* wsrc = conv_w + (size_t)c * (DL * KS);
        for (int idx = tid; idx < DL * KS; idx += 256) wsm[idx / KS][idx % KS] = wsrc[idx];
        es[tid >> 6][tid & 63] = emb[tid];
        __syncthreads();
        if (tid < 60) {
            const int v = tid / KS, k = tid % KS;
            float s = 0.f;
#pragma unroll
            for (int i = 0; i < DL; ++i) s += es[v][i] * wsm[i][k];
            g_ctb[tid * DC + c] = s;
        }
    }
}

template <int NW>
__device__ __forceinline__ float bsum(float v, float* red, int tid) {
#pragma unroll
    for (int off = 32; off > 0; off >>= 1) v += __shfl_down(v, off, 64);
    if ((tid & 63) == 0) red[tid >> 6] = v;
    __syncthreads();
    float r = 0.f;
#pragma unroll
    for (int w = 0; w < NW; ++w) r += red[w];
    __syncthreads();
    return r;
}

template <int NW>
__device__ __forceinline__ float bmax(float v, float* red, int tid) {
#pragma unroll
    for (int off = 32; off > 0; off >>= 1) v = fmaxf(v, __shfl_down(v, off, 64));
    if ((tid & 63) == 0) red[tid >> 6] = v;
    __syncthreads();
    float r = red[0];
#pragma unroll
    for (int w = 1; w < NW; ++w) r = fmaxf(r, red[w]);
    __syncthreads();
    return r;
}

// ---------------- K2: everything per sequence, one block, one barrier-light pass ----------------
// wave0 runs the scalar chain wave-synchronously (no barriers) while waves 1-7 stage tokens.
__global__ __launch_bounds__(512) void encode_kernel(
    const float* __restrict__ conv_b,
    const float* __restrict__ Wq, const float* __restrict__ bq,
    const float* __restrict__ Wk, const float* __restrict__ bk,
    const float* __restrict__ Wv, const float* __restrict__ bv,
    float* __restrict__ out) {
    const int n = blockIdx.x, tid = threadIdx.x;
    const float* ctb = g_ctb;
    const unsigned* packed = g_pack;

    __shared__ unsigned tok2L[258];
    __shared__ float stabL[64];
    __shared__ float cfL[60];
    __shared__ float rmL[DC], qvL[DC], qkL[DC], zvL[DC];
    __shared__ float Tt[1024];
    __shared__ float AccL[45];
    __shared__ float red[8];

    if (tid >= 64) {
        const int i = tid - 64;
        if (i < 258) tok2L[i] = (i < 256) ? packed[n * 256 + i] : 0u;
        else if (i < 258 + 45) AccL[i - 258] = 0.f;
    } else {
        // ======== wave0: counts -> rm -> q -> qk -> stab/base, wave-synchronous ========
        const int l = tid;
        const int4 ct = *(const int4*)(g_cnt + n * 4);
        const unsigned dwF = packed[n * 256];          // tokens 0..15
        const unsigned dwL = packed[n * 256 + 255];    // tokens 4080..4095
        if (l < KS) {
            const int k = l;
            const unsigned pm = (k == 0) ? 0u : ((1u << (2 * k)) - 1u);          // slots [0,k)
            const unsigned sm = (k == 14) ? 0u : (0xFFFFFFFFu << (2 * (k + 2))); // slots [k+2,16)
            const int tot4[4] = {ct.x, ct.y, ct.z, ct.w};
#pragma unroll
            for (int v = 0; v < 4; ++v) {
                const unsigned patt = (unsigned)v * 0x55555555u;
                unsigned yf = dwF ^ patt, zf = (yf | (yf >> 1)) & 0x55555555u;
                unsigned yl = dwL ^ patt, zl = (yl | (yl >> 1)) & 0x55555555u;
                const int pre = k - __popc(zf & pm);          // #v in [0,k)
                const int suf = (14 - k) - __popc(zl & sm);   // #v in [k+LOUT, LL)
                cfL[v * KS + k] = (float)(tot4[v] - pre - suf);
            }
        }
        const int c0 = 2 * l, c1 = 2 * l + 1;
        // rm
        float r0 = 0.f, r1 = 0.f;
        for (int j = 0; j < 60; ++j) {
            const float cfj = cfL[j];
            const float2 cb = *(const float2*)(ctb + j * DC + c0);
            r0 += cfj * cb.x; r1 += cfj * cb.y;
        }
        const float2 cb2 = *(const float2*)(conv_b + c0);
        r0 = cb2.x + r0 * INV_LOUT; r1 = cb2.y + r1 * INV_LOUT;
        rmL[c0] = r0; rmL[c1] = r1;
        // q = rm @ Wq.T + bq
        const float4* wq0 = (const float4*)(Wq + (size_t)c0 * DC);
        const float4* wq1 = (const float4*)(Wq + (size_t)c1 * DC);
        const float4* rr = (const float4*)rmL;
        float s0 = 0.f, s1 = 0.f;
#pragma unroll 8
        for (int j = 0; j < 32; ++j) {
            const float4 r = rr[j], a = wq0[j], b = wq1[j];
            s0 += a.x * r.x + a.y * r.y + a.z * r.z + a.w * r.w;
            s1 += b.x * r.x + b.y * r.y + b.z * r.z + b.w * r.w;
        }
        const float2 bq2 = *(const float2*)(bq + c0);
        const float qv0 = s0 + bq2.x, qv1 = s1 + bq2.y;
        qvL[c0] = qv0; qvL[c1] = qv1;
        // qk[d] = sum_c q[c] * Wk[c,d]  (coalesced columns)
        float k0 = 0.f, k1 = 0.f;
        const float4* qq = (const float4*)qvL;
        for (int c4 = 0; c4 < 32; ++c4) {
            const float4 q4 = qq[c4];
            const float2 w0 = *(const float2*)(Wk + (size_t)(4 * c4 + 0) * DC + c0);
            const float2 w1 = *(const float2*)(Wk + (size_t)(4 * c4 + 1) * DC + c0);
            const float2 w2 = *(const float2*)(Wk + (size_t)(4 * c4 + 2) * DC + c0);
            const float2 w3 = *(const float2*)(Wk + (size_t)(4 * c4 + 3) * DC + c0);
            k0 += q4.x * w0.x + q4.y * w1.x + q4.z * w2.x + q4.w * w3.x;
            k1 += q4.x * w0.y + q4.y * w1.y + q4.z * w2.y + q4.w * w3.y;
        }
        qkL[c0] = k0; qkL[c1] = k1;
        // stab[j] = (ctb[j] . qk) / sqrt(DC)
        if (l < 60) {
            const float4* cr = (const float4*)(ctb + (size_t)l * DC);
            const float4* qk4 = (const float4*)qkL;
            float s = 0.f;
#pragma unroll 8
            for (int t = 0; t < 32; ++t) {
                const float4 a = cr[t], q = qk4[t];
                s += a.x * q.x + a.y * q.y + a.z * q.z + a.w * q.w;
            }
            stabL[l] = s * RSQRT_DC;
        }
        // base = (conv_b . qk + q . bk) / sqrt(DC)
        const float2 bk2 = *(const float2*)(bk + c0);
        float t = cb2.x * k0 + cb2.y * k1 + qv0 * bk2.x + qv1 * bk2.y;
#pragma unroll
        for (int off = 32; off > 0; off >>= 1) t += __shfl_down(t, off, 64);
        if (l == 0) stabL[60] = t * RSQRT_DC;
    }
    __syncthreads();

    // ---- chunk tables: Tt[j*256+b] = sum_m stab[tok_m(b)*15 + 4j+m] ----
    const float base = stabL[60];
    for (int e = tid; e < 1024; e += 512) {
        const int j = e >> 8, bb = e & 255;
        float s = stabL[(bb & 3) * KS + 4 * j] +
                  stabL[((bb >> 2) & 3) * KS + 4 * j + 1] +
                  stabL[((bb >> 4) & 3) * KS + 4 * j + 2];
        if (j < 3) s += stabL[((bb >> 6) & 3) * KS + 4 * j + 3];
        Tt[e] = s;
    }
    __syncthreads();

    // ---- scores: 8 consecutive positions/thread from a 64-bit register window ----
    const unsigned d0 = tok2L[tid >> 1], d1 = tok2L[(tid >> 1) + 1];
    const unsigned long long W = (unsigned long long)d0 | ((unsigned long long)d1 << 32);
    const int sbase = (tid & 1) << 4;
    const int t0 = tid * 8;
    float sc[8];
    float lmax = -3.4e38f;
#pragma unroll
    for (int p = 0; p < 8; ++p) {
        const unsigned w = (unsigned)(W >> (sbase + 2 * p));
        const float s = base + Tt[w & 255] + Tt[256 + ((w >> 8) & 255)] +
                        Tt[512 + ((w >> 16) & 255)] + Tt[768 + ((w >> 24) & 63)];
        sc[p] = (t0 + p < LOUT) ? s : -3.4e38f;
        lmax = fmaxf(lmax, sc[p]);
    }
    const float m = bmax<8>(lmax, red, tid);
    float lsum = 0.f;
#pragma unroll
    for (int p = 0; p < 8; ++p) {
        const float e = (t0 + p < LOUT) ? __expf(sc[p] - m) : 0.f;
        sc[p] = e; lsum += e;
    }
    const float S = bsum<8>(lsum, red, tid);
    const float invS = 1.0f / S;

    // ---- attn-weighted histogram (v=0 recovered from S) ----
    float a1[KS], a2[KS], a3[KS];
#pragma unroll
    for (int k = 0; k < KS; ++k) { a1[k] = 0.f; a2[k] = 0.f; a3[k] = 0.f; }
#pragma unroll
    for (int p = 0; p < 8; ++p) {
        const float e = sc[p];
        const unsigned w = (unsigned)(W >> (sbase + 2 * p));
#pragma unroll
        for (int k = 0; k < KS; ++k) {
            const int v = (int)((w >> (2 * k)) & 3u);
            a1[k] += (v == 1) ? e : 0.f;
            a2[k] += (v == 2) ? e : 0.f;
            a3[k] += (v == 3) ? e : 0.f;
        }
    }
    {
        const int lane = tid & 63;
#pragma unroll
        for (int k = 0; k < KS; ++k) {
            float v1 = a1[k], v2 = a2[k], v3 = a3[k];
#pragma unroll
            for (int off = 32; off > 0; off >>= 1) {
                v1 += __shfl_down(v1, off, 64);
                v2 += __shfl_down(v2, off, 64);
                v3 += __shfl_down(v3, off, 64);
            }
            if (lane == 0) {
                atomicAdd(&AccL[k], v1);
                atomicAdd(&AccL[KS + k], v2);
                atomicAdd(&AccL[2 * KS + k], v3);
            }
        }
    }
    __syncthreads();

    // ---- z = conv_b + (1/S) * sum_j Acc[j] * ctb[j] ----
    if (tid < DC) {
        float s = 0.f;
#pragma unroll
        for (int k = 0; k < KS; ++k) {
            const float a0 = S - AccL[k] - AccL[KS + k] - AccL[2 * KS + k];
            s += a0 * ctb[k * DC + tid];
        }
#pragma unroll
        for (int j = KS; j < 60; ++j) s += AccL[j - KS] * ctb[j * DC + tid];
        zvL[tid] = conv_b[tid] + s * invS;
    }
    __syncthreads();

    // ---- out = z @ Wv.T + bv ----
    if (tid < DC) {
        const float4* wr = (const float4*)(Wv + (size_t)tid * DC);
        const float4* z4 = (const float4*)zvL;
        float s = 0.f;
#pragma unroll 8
        for (int j = 0; j < 32; ++j) {
            const float4 w = wr[j], z = z4[j];
            s += w.x * z.x + w.y * z.y + w.z * z.z + w.w * z.w;
        }
        out[(size_t)n * DC + tid] = s + bv[tid];
    }
}

extern "C" void kernel_launch(void* const* d_in, const int* in_sizes, int n_in,
                              void* d_out, int out_size, void* d_ws, size_t ws_size,
                              hipStream_t stream) {
    const int*   tokens = (const int*)d_in[0];
    const float* emb    = (const float*)d_in[1];
    const float* conv_w = (const float*)d_in[2];
    const float* conv_b = (const float*)d_in[3];
    const float* Wq     = (const float*)d_in[4];
    const float* bq     = (const float*)d_in[5];
    const float* Wk     = (const float*)d_in[6];
    const float* bk     = (const float*)d_in[7];
    const float* Wv     = (const float*)d_in[8];
    const float* bv     = (const float*)d_in[9];
    float* out = (float*)d_out;
    (void)d_ws; (void)ws_size;   // workspace intentionally unused

    prep_kernel<<<NN + DC, 256, 0, stream>>>(tokens, emb, conv_w);
    encode_kernel<<<NN, 512, 0, stream>>>(conv_b, Wq, bq, Wk, bk, Wv, bv, out);
}